// Round 6
// baseline (177.414 us; speedup 1.0000x reference)
//
#include <hip/hip_runtime.h>
#include <hip/hip_bf16.h>

// GAT encoder: B=16, N=768, IN=16, HID=64, HEADS=8, EMB=128, 2 GAT layers.
// Round 6: cut operand-traffic amplification.
//  - LDS-stage shared B-fragments (global_load_lds w16, 2-phase dbuf) in
//    k_attn / k_wh2 / k_projm (was: 4 waves x redundant L2 loads).
//  - XCD swizzle: h = bid&7 so each (b,h) slab (Whf/s1/s2/W-frags) stays in
//    one XCD's L2 across producer and consumer kernels.
//  - k_cvtw + k_h0frag merged into k_prep. Math identical to round 5.
//
// ws: h0A us[786432] | Whf us[6291456] | s1 f[98304] | s2 f[98304]
//     | hpA us[6291456] | W1f us[262144] | pwf us[65536] | W0f us[32768]

#define B_ 16
#define N_ 768
#define IN_DIM_ 16
#define HID_ 64
#define EMB_ 128
#define NH_ 8
#define F1_ (NH_ * HID_) // 512
#define LOG2E_ 1.4426950408889634f

typedef __attribute__((ext_vector_type(4))) float f32x4;
typedef __attribute__((ext_vector_type(8))) short bf16x8;

typedef __attribute__((address_space(1))) const unsigned int gu32;
typedef __attribute__((address_space(3))) unsigned int lu32;

static __device__ __forceinline__ void gload_lds16(const void* g, void* l) {
    // async global->LDS, 16B per lane; LDS dest = wave-uniform base + lane*16
    __builtin_amdgcn_global_load_lds((gu32*)g, (lu32*)l, 16, 0, 0);
}

static __device__ __forceinline__ short f2bf(float x) {
    __hip_bfloat16 b = __float2bfloat16(x);
    return *reinterpret_cast<short*>(&b);
}

// ---- prep: input projection -> h0A A-fragments, plus W1f/pwf/W0f converts ----
// h0A[rtg][kt][lane][8]: value h0[rtg*16+(l&15)][kt*32+(l>>4)*8+j]
__global__ __launch_bounds__(256) void k_prep(const float* __restrict__ x,
                                              const float* __restrict__ ipw,
                                              const float* __restrict__ ipb,
                                              const float* __restrict__ w1,
                                              const float* __restrict__ pw,
                                              const float* __restrict__ w0,
                                              ushort* __restrict__ h0A,
                                              ushort* __restrict__ W1f,
                                              ushort* __restrict__ pwf,
                                              ushort* __restrict__ W0f) {
    if (blockIdx.x < 384) {
        const int t = blockIdx.x * 256 + threadIdx.x;  // < 98304
        const int lane = t & 63;
        const int kt = (t >> 6) & 1;
        const int rtg = t >> 7;
        const int row = rtg * 16 + (lane & 15);
        const int k0 = kt * 32 + (lane >> 4) * 8;
        const float* xr = x + row * IN_DIM_;
        float xv[IN_DIM_];
#pragma unroll
        for (int f = 0; f < IN_DIM_; ++f) xv[f] = xr[f];
        bf16x8 v;
#pragma unroll
        for (int j = 0; j < 8; ++j) {
            float acc = ipb[k0 + j];
#pragma unroll
            for (int f = 0; f < IN_DIM_; ++f) acc = fmaf(xv[f], ipw[f * HID_ + k0 + j], acc);
            v[j] = f2bf(acc);
        }
        *(bf16x8*)&h0A[t * 8] = v;
        return;
    }
    int t = (blockIdx.x - 384) * 256 + threadIdx.x;  // < 45056
    if (t < 32768) {
        int lane = t & 63, nt = (t >> 6) & 3, kt = (t >> 8) & 15, h = t >> 12;
        int k0 = kt * 32 + (lane >> 4) * 8;
        int col = nt * 16 + (lane & 15);
        const float* src = w1 + (h * 512 + k0) * 64 + col;
        bf16x8 v;
#pragma unroll
        for (int j = 0; j < 8; ++j) v[j] = f2bf(src[j * 64]);
        *(bf16x8*)&W1f[t * 8] = v;
    } else if (t < 40960) {
        int u = t - 32768;  // < 8192
        int lane = u & 63, nt = (u >> 6) & 7, kt = u >> 9;
        int k0 = kt * 32 + (lane >> 4) * 8;
        int col = nt * 16 + (lane & 15);
        const float* src = pw + k0 * 128 + col;
        bf16x8 v;
#pragma unroll
        for (int j = 0; j < 8; ++j) v[j] = f2bf(src[j * 128]);
        *(bf16x8*)&pwf[u * 8] = v;
    } else {
        int u = t - 40960;  // < 4096
        int lane = u & 63, nt = (u >> 6) & 3, kt = (u >> 8) & 1, h = u >> 9;
        int k0 = kt * 32 + (lane >> 4) * 8;
        int col = nt * 16 + (lane & 15);
        const float* src = w0 + (h * 64 + k0) * 64 + col;
        bf16x8 v;
#pragma unroll
        for (int j = 0; j < 8; ++j) v[j] = f2bf(src[j * 64]);
        *(bf16x8*)&W0f[u * 8] = v;
    }
}

#define TBSTRIDE 40

// -------- layer-0 Wh GEMM on MFMA (K=64) + fused s1/s2 + Whf B-frags --------
// XCD swizzle: h = bid&7 (Whf/s1/s2 for (b,h) stay on one XCD with k_attn).
__global__ __launch_bounds__(256) void k_wh1m(const ushort* __restrict__ h0A,
                                              const ushort* __restrict__ W0f,
                                              const float* __restrict__ a,
                                              ushort* __restrict__ Whf,
                                              float* __restrict__ s1,
                                              float* __restrict__ s2) {
    __shared__ __align__(16) ushort tb[4][64 * TBSTRIDE];
    const int bid = blockIdx.x;
    const int h = bid & 7;
    const int rest = bid >> 3;          // 0..95
    const int b = rest & 15;
    const int chunk = rest >> 4;        // 0..5
    const int bh = b * NH_ + h;

    const int lane = threadIdx.x & 63;
    const int w = threadIdx.x >> 6;
    const int lg = lane >> 4;
    const int ll = lane & 15;

    f32x4 zero4 = {0.f, 0.f, 0.f, 0.f};
    f32x4 acc[2][4];
#pragma unroll
    for (int mt = 0; mt < 2; ++mt)
#pragma unroll
        for (int nt = 0; nt < 4; ++nt) acc[mt][nt] = zero4;

    const int rt0 = b * 48 + chunk * 8 + w * 2;
#pragma unroll
    for (int kt = 0; kt < 2; ++kt) {
        bf16x8 afr[2];
#pragma unroll
        for (int mt = 0; mt < 2; ++mt)
            afr[mt] = *(const bf16x8*)&h0A[(((rt0 + mt) * 2) + kt) * 512 + lane * 8];
        bf16x8 bfr[4];
#pragma unroll
        for (int nt = 0; nt < 4; ++nt)
            bfr[nt] = *(const bf16x8*)&W0f[(((h * 2 + kt) * 4) + nt) * 512 + lane * 8];
#pragma unroll
        for (int mt = 0; mt < 2; ++mt)
#pragma unroll
            for (int nt = 0; nt < 4; ++nt)
                acc[mt][nt] = __builtin_amdgcn_mfma_f32_16x16x32_bf16(afr[mt], bfr[nt], acc[mt][nt], 0, 0, 0);
    }

    float a1v[4], a2v[4];
#pragma unroll
    for (int nt = 0; nt < 4; ++nt) {
        a1v[nt] = a[h * 2 * HID_ + nt * 16 + ll];
        a2v[nt] = a[h * 2 * HID_ + HID_ + nt * 16 + ll];
    }
    const int n0 = chunk * 128;
    float* s1b = s1 + bh * N_ + n0 + w * 32;
    float* s2b = s2 + bh * N_ + n0 + w * 32;
    ushort* tbw = tb[w];
#pragma unroll
    for (int mt = 0; mt < 2; ++mt) {
#pragma unroll
        for (int reg = 0; reg < 4; ++reg) {
            const int r32 = mt * 16 + lg * 4 + reg;
            float p1 = 0.f, p2 = 0.f;
#pragma unroll
            for (int nt = 0; nt < 4; ++nt) {
                float v = acc[mt][nt][reg];
                p1 = fmaf(v, a1v[nt], p1);
                p2 = fmaf(v, a2v[nt], p2);
            }
#pragma unroll
            for (int off = 8; off; off >>= 1) {
                p1 += __shfl_xor(p1, off);
                p2 += __shfl_xor(p2, off);
            }
            if (ll == 0) {
                s1b[r32] = p1;
                s2b[r32] = p2;
            }
#pragma unroll
            for (int nt = 0; nt < 4; ++nt) {
                int c = nt * 16 + ll;
                tbw[c * TBSTRIDE + r32] = (ushort)f2bf(acc[mt][nt][reg]);
            }
        }
    }
    __syncthreads();

    const int kt2 = chunk * 4 + w;
#pragma unroll
    for (int nt = 0; nt < 4; ++nt) {
        int c = nt * 16 + ll;
        bf16x8 v = *(const bf16x8*)&tbw[c * TBSTRIDE + lg * 8];
        *(bf16x8*)&Whf[(bh * 24 + kt2) * 2048 + nt * 512 + lane * 8] = v;
    }
}

// ---- fused attention on MFMA; B-tiles LDS-staged (2-phase dbuf); h=bid&7 ----
__global__ __launch_bounds__(256) void k_attn(const ushort* __restrict__ Whf,
                                              const float* __restrict__ s1,
                                              const float* __restrict__ s2,
                                              ushort* __restrict__ hpA) {
    __shared__ __align__(16) float t1s[128];
    __shared__ __align__(16) float t2s[N_];
    __shared__ __align__(16) float dls[128];
    __shared__ __align__(16) ushort hbuf[128 * 64];   // swizzled [row][col]
    __shared__ __align__(16) ushort sbuf[2][2048];    // staged Whf K-tile
    const int bid = blockIdx.x;
    const int h = bid & 7;
    const int rest = bid >> 3;          // 0..95
    const int b = rest & 15;
    const int nc = rest >> 4;           // 0..5
    const int n0 = nc * 128;
    const int bh = b * NH_ + h;

    const int lane = threadIdx.x & 63;
    const int w = threadIdx.x >> 6;

    const float* s1g = s1 + bh * N_;
    const float* s2g = s2 + bh * N_;
    for (int i = threadIdx.x; i < N_; i += 256) t2s[i] = s2g[i] * LOG2E_;
    if (threadIdx.x < 128) t1s[threadIdx.x] = s1g[n0 + threadIdx.x] * LOG2E_;

    const ushort* Wbase = Whf + bh * ((N_ / 32) * 2048);
    // stage tile 0 (lane scatter is HW: dest = wave base + lane*16B)
    gload_lds16(Wbase + threadIdx.x * 8, &sbuf[0][w * 512]);

    const int rowbase = w * 32;
    const int lg = lane >> 4;
    const int ll = lane & 15;

    f32x4 zero4 = {0.f, 0.f, 0.f, 0.f};
    f32x4 acc[2][4];
    f32x4 dacc[2];
#pragma unroll
    for (int mt = 0; mt < 2; ++mt) {
        dacc[mt] = zero4;
#pragma unroll
        for (int nt = 0; nt < 4; ++nt) acc[mt][nt] = zero4;
    }

    bf16x8 onesB;
#pragma unroll
    for (int j = 0; j < 8; ++j) onesB[j] = (ll == 0) ? (short)0x3F80 : (short)0;

    float t1a = 0.f, t1b = 0.f;
    int cur = 0;
    for (int ktile = 0; ktile < N_ / 32; ++ktile) {
        __syncthreads();  // stage(cur) done (vmcnt drained) + prev reads of buf[cur^1] done
        if (ktile == 0) {
            t1a = t1s[rowbase + ll];
            t1b = t1s[rowbase + 16 + ll];
        }
        if (ktile + 1 < N_ / 32)
            gload_lds16(Wbase + (ktile + 1) * 2048 + threadIdx.x * 8, &sbuf[cur ^ 1][w * 512]);

        const ushort* sb = sbuf[cur];
        bf16x8 bq[4];
#pragma unroll
        for (int nt = 0; nt < 4; ++nt) bq[nt] = *(const bf16x8*)&sb[nt * 512 + lane * 8];

        float qv[8];
        const float* q = &t2s[ktile * 32 + lg * 8];
#pragma unroll
        for (int j = 0; j < 8; ++j) qv[j] = q[j];

#pragma unroll
        for (int mt = 0; mt < 2; ++mt) {
            const float t1v = mt ? t1b : t1a;
            bf16x8 af;
#pragma unroll
            for (int j = 0; j < 8; ++j) {
                float e = t1v + qv[j];
                e = fmaxf(e, 0.2f * e);   // leaky_relu (log2-scaled; scale>0 commutes)
                af[j] = f2bf(exp2f(e));
            }
            dacc[mt] = __builtin_amdgcn_mfma_f32_16x16x32_bf16(af, onesB, dacc[mt], 0, 0, 0);
#pragma unroll
            for (int nt = 0; nt < 4; ++nt)
                acc[mt][nt] = __builtin_amdgcn_mfma_f32_16x16x32_bf16(af, bq[nt], acc[mt][nt], 0, 0, 0);
        }
        cur ^= 1;
    }

#pragma unroll
    for (int mt = 0; mt < 2; ++mt) {
        if (ll == 0) {
#pragma unroll
            for (int reg = 0; reg < 4; ++reg)
                dls[rowbase + mt * 16 + lg * 4 + reg] = dacc[mt][reg];
        }
    }
    __syncthreads();

    // scale + swizzled bf16 store to LDS (row stride 128B, swz<128: bijective)
    char* hb8 = (char*)hbuf;
#pragma unroll
    for (int mt = 0; mt < 2; ++mt) {
#pragma unroll
        for (int reg = 0; reg < 4; ++reg) {
            const int row = rowbase + mt * 16 + lg * 4 + reg;
            const float inv = 1.0f / dls[row];
            const int swz = (row & 7) << 4;
#pragma unroll
            for (int nt = 0; nt < 4; ++nt) {
                int c = nt * 16 + ll;
                *(ushort*)(hb8 + row * 128 + ((c * 2) ^ swz)) =
                    (ushort)f2bf(acc[mt][nt][reg] * inv);
            }
        }
    }
    __syncthreads();

    // fragment read + coalesced global store
    // hpA[rtg][kc][lane][8]; value = hp[rtg*16+(l&15)][kc*32+(l>>4)*8+j]
#pragma unroll
    for (int rt2 = 0; rt2 < 2; ++rt2) {
#pragma unroll
        for (int kc = 0; kc < 2; ++kc) {
            const int rtl = w * 2 + rt2;
            const int row = rtl * 16 + ll;
            bf16x8 v = *(const bf16x8*)(hb8 + row * 128 +
                                        (((kc * 64 + lg * 16)) ^ ((row & 7) << 4)));
            const int rtg = b * 48 + nc * 8 + rtl;
            *(bf16x8*)&hpA[((rtg * 16) + (h * 2 + kc)) * 512 + lane * 8] = v;
        }
    }
}

// -------- layer-1 Wh GEMM on MFMA + s1/s2 + Whf frags; W1f LDS-staged --------
__global__ __launch_bounds__(256) void k_wh2(const ushort* __restrict__ hpA,
                                             const ushort* __restrict__ W1f,
                                             const float* __restrict__ a,
                                             ushort* __restrict__ Whf,
                                             float* __restrict__ s1,
                                             float* __restrict__ s2) {
    __shared__ __align__(16) ushort tb[4][64 * TBSTRIDE];
    __shared__ __align__(16) ushort sbuf[2][2048];
    const int bid = blockIdx.x;
    const int h = bid & 7;
    const int rest = bid >> 3;
    const int b = rest & 15;
    const int chunk = rest >> 4;
    const int bh = b * NH_ + h;

    const int lane = threadIdx.x & 63;
    const int w = threadIdx.x >> 6;
    const int lg = lane >> 4;
    const int ll = lane & 15;

    f32x4 zero4 = {0.f, 0.f, 0.f, 0.f};
    f32x4 acc[2][4];
#pragma unroll
    for (int mt = 0; mt < 2; ++mt)
#pragma unroll
        for (int nt = 0; nt < 4; ++nt) acc[mt][nt] = zero4;

    const ushort* W1base = W1f + h * 16 * 2048;
    gload_lds16(W1base + threadIdx.x * 8, &sbuf[0][w * 512]);

    const int rt0 = b * 48 + chunk * 8 + w * 2;
    int cur = 0;
    for (int kt = 0; kt < 16; ++kt) {
        __syncthreads();
        if (kt + 1 < 16)
            gload_lds16(W1base + (kt + 1) * 2048 + threadIdx.x * 8, &sbuf[cur ^ 1][w * 512]);
        bf16x8 afr[2];
#pragma unroll
        for (int mt = 0; mt < 2; ++mt)
            afr[mt] = *(const bf16x8*)&hpA[(((rt0 + mt) * 16) + kt) * 512 + lane * 8];
        const ushort* sb = sbuf[cur];
        bf16x8 bfr[4];
#pragma unroll
        for (int nt = 0; nt < 4; ++nt)
            bfr[nt] = *(const bf16x8*)&sb[nt * 512 + lane * 8];
#pragma unroll
        for (int mt = 0; mt < 2; ++mt)
#pragma unroll
            for (int nt = 0; nt < 4; ++nt)
                acc[mt][nt] = __builtin_amdgcn_mfma_f32_16x16x32_bf16(afr[mt], bfr[nt], acc[mt][nt], 0, 0, 0);
        cur ^= 1;
    }

    float a1v[4], a2v[4];
#pragma unroll
    for (int nt = 0; nt < 4; ++nt) {
        a1v[nt] = a[h * 2 * HID_ + nt * 16 + ll];
        a2v[nt] = a[h * 2 * HID_ + HID_ + nt * 16 + ll];
    }
    const int n0 = chunk * 128;
    float* s1b = s1 + bh * N_ + n0 + w * 32;
    float* s2b = s2 + bh * N_ + n0 + w * 32;
    ushort* tbw = tb[w];
#pragma unroll
    for (int mt = 0; mt < 2; ++mt) {
#pragma unroll
        for (int reg = 0; reg < 4; ++reg) {
            const int r32 = mt * 16 + lg * 4 + reg;
            float p1 = 0.f, p2 = 0.f;
#pragma unroll
            for (int nt = 0; nt < 4; ++nt) {
                float v = acc[mt][nt][reg];
                p1 = fmaf(v, a1v[nt], p1);
                p2 = fmaf(v, a2v[nt], p2);
            }
#pragma unroll
            for (int off = 8; off; off >>= 1) {
                p1 += __shfl_xor(p1, off);
                p2 += __shfl_xor(p2, off);
            }
            if (ll == 0) {
                s1b[r32] = p1;
                s2b[r32] = p2;
            }
#pragma unroll
            for (int nt = 0; nt < 4; ++nt) {
                int c = nt * 16 + ll;
                tbw[c * TBSTRIDE + r32] = (ushort)f2bf(acc[mt][nt][reg]);
            }
        }
    }
    __syncthreads();

    const int kt2 = chunk * 4 + w;
#pragma unroll
    for (int nt = 0; nt < 4; ++nt) {
        int c = nt * 16 + ll;
        bf16x8 v = *(const bf16x8*)&tbw[c * TBSTRIDE + lg * 8];
        *(bf16x8*)&Whf[(bh * 24 + kt2) * 2048 + nt * 512 + lane * 8] = v;
    }
}

// -------- output projection on MFMA; pwf LDS-staged (2-phase dbuf) --------
__global__ __launch_bounds__(256) void k_projm(const ushort* __restrict__ hpA,
                                               const ushort* __restrict__ pwf,
                                               const float* __restrict__ bias,
                                               float* __restrict__ out) {
    __shared__ __align__(16) ushort sbuf[2][4096];
    const int blk = blockIdx.x;          // 384 blocks, 32 rows each
    const int lane = threadIdx.x & 63;
    const int w = threadIdx.x >> 6;
    const int wrow = w >> 1, wcol = w & 1;
    const int lg = lane >> 4;
    const int ll = lane & 15;

    f32x4 zero4 = {0.f, 0.f, 0.f, 0.f};
    f32x4 acc[4];
#pragma unroll
    for (int nt = 0; nt < 4; ++nt) acc[nt] = zero4;

    // stage kt=0 row (8KB = 2 rounds of 256x16B)
    gload_lds16(pwf + threadIdx.x * 8, &sbuf[0][w * 512]);
    gload_lds16(pwf + 2048 + threadIdx.x * 8, &sbuf[0][2048 + w * 512]);

    const int rt = blk * 2 + wrow;
    int cur = 0;
    for (int kt = 0; kt < 16; ++kt) {
        __syncthreads();
        if (kt + 1 < 16) {
            const ushort* row = pwf + (kt + 1) * 4096;
            gload_lds16(row + threadIdx.x * 8, &sbuf[cur ^ 1][w * 512]);
            gload_lds16(row + 2048 + threadIdx.x * 8, &sbuf[cur ^ 1][2048 + w * 512]);
        }
        bf16x8 afr = *(const bf16x8*)&hpA[((rt * 16) + kt) * 512 + lane * 8];
        const ushort* sb = sbuf[cur];
        bf16x8 bfr[4];
#pragma unroll
        for (int nt = 0; nt < 4; ++nt)
            bfr[nt] = *(const bf16x8*)&sb[(wcol * 4 + nt) * 512 + lane * 8];
#pragma unroll
        for (int nt = 0; nt < 4; ++nt)
            acc[nt] = __builtin_amdgcn_mfma_f32_16x16x32_bf16(afr, bfr[nt], acc[nt], 0, 0, 0);
        cur ^= 1;
    }

#pragma unroll
    for (int reg = 0; reg < 4; ++reg) {
        const int row = blk * 32 + wrow * 16 + lg * 4 + reg;
#pragma unroll
        for (int nt = 0; nt < 4; ++nt) {
            const int col = wcol * 64 + nt * 16 + ll;
            out[row * EMB_ + col] = acc[nt][reg] + bias[col];
        }
    }
}

extern "C" void kernel_launch(void* const* d_in, const int* in_sizes, int n_in,
                              void* d_out, int out_size, void* d_ws, size_t ws_size,
                              hipStream_t stream) {
    const float* x    = (const float*)d_in[0];
    const float* ip_w = (const float*)d_in[1];
    const float* ip_b = (const float*)d_in[2];
    const float* gw0  = (const float*)d_in[3];
    const float* ga0  = (const float*)d_in[4];
    const float* gw1  = (const float*)d_in[5];
    const float* ga1  = (const float*)d_in[6];
    const float* pw   = (const float*)d_in[7];
    const float* pb   = (const float*)d_in[8];
    float* out = (float*)d_out;

    ushort* h0A = (ushort*)d_ws;                      // 786432 us
    ushort* Whf = h0A + 786432;                       // 6291456 us
    float* s1 = (float*)(Whf + 6291456);              // 98304 f
    float* s2 = s1 + B_ * NH_ * N_;                   // 98304 f
    ushort* hpA = (ushort*)(s2 + B_ * NH_ * N_);      // 6291456 us
    ushort* W1f = hpA + 6291456;                      // 262144 us
    ushort* pwf = W1f + 262144;                       // 65536 us
    ushort* W0f = pwf + 65536;                        // 32768 us

    const int gat_blocks = 768;   // 8 h-groups (XCD) x 16 b x 6 chunks

    k_prep<<<560, 256, 0, stream>>>(x, ip_w, ip_b, gw1, pw, gw0, h0A, W1f, pwf, W0f);
    k_wh1m<<<gat_blocks, 256, 0, stream>>>(h0A, W0f, ga0, Whf, s1, s2);
    k_attn<<<gat_blocks, 256, 0, stream>>>(Whf, s1, s2, hpA);
    k_wh2<<<gat_blocks, 256, 0, stream>>>(hpA, W1f, ga1, Whf, s1, s2);
    k_attn<<<gat_blocks, 256, 0, stream>>>(Whf, s1, s2, hpA);
    k_projm<<<(B_ * N_) / 32, 256, 0, stream>>>(hpA, pwf, pb, out);
}